// Round 8
// baseline (631.539 us; speedup 1.0000x reference)
//
#include <hip/hip_runtime.h>
#include <hip/hip_bf16.h>
#include <math.h>

#define N_NODES_C 50000
#define N_EDGES_C 800000
#define DIM 512
#define NUM_GRAPHS_C 64
#define NUM_CLASSES_C 10

#define NROWT ((N_NODES_C + 127) / 128)              // 391 row-tiles
#define GEMM_BLOCKS (((NROWT * 4 + 31) / 32) * 32)   // 1568 (pad to swizzle group)

#define SCAN_BLK 1024
#define SCAN_NBLK ((N_NODES_C + SCAN_BLK - 1) / SCAN_BLK)  // 49 (<= 64)

typedef short bf16x8 __attribute__((ext_vector_type(8)));
typedef short bf16x4 __attribute__((ext_vector_type(4)));
typedef float f32x4 __attribute__((ext_vector_type(4)));
typedef float f32x2 __attribute__((ext_vector_type(2)));
typedef unsigned u32x2 __attribute__((ext_vector_type(2)));

__device__ __forceinline__ float bf2f(short s) {
    return __uint_as_float(((unsigned)(unsigned short)s) << 16);
}
__device__ __forceinline__ short f2bf(float f) {
    unsigned u = __float_as_uint(f);
    u += 0x7FFF + ((u >> 16) & 1);  // RNE
    return (short)(u >> 16);
}
// fast ELU: expf-1 instead of expm1f; abs err ~1e-7, invisible in bf16 out
__device__ __forceinline__ float eluf(float v) {
    return v > 0.0f ? v : __expf(v) - 1.0f;
}
__device__ __forceinline__ unsigned f32x4_to_fp8(float a, float b, float c, float d) {
    int w = 0;
    w = __builtin_amdgcn_cvt_pk_fp8_f32(a, b, w, false);
    w = __builtin_amdgcn_cvt_pk_fp8_f32(c, d, w, true);
    return (unsigned)w;
}
__device__ __forceinline__ void acc_fp8x8(float* acc, u32x2 w) {
    f32x2 a = __builtin_amdgcn_cvt_pk_f32_fp8((int)w[0], false);
    f32x2 b = __builtin_amdgcn_cvt_pk_f32_fp8((int)w[0], true);
    f32x2 c = __builtin_amdgcn_cvt_pk_f32_fp8((int)w[1], false);
    f32x2 d = __builtin_amdgcn_cvt_pk_f32_fp8((int)w[1], true);
    acc[0] += a[0]; acc[1] += a[1]; acc[2] += b[0]; acc[3] += b[1];
    acc[4] += c[0]; acc[5] += c[1]; acc[6] += d[0]; acc[7] += d[1];
}

// async global->LDS, 16B per lane; LDS dest = wave-uniform base + lane*16
__device__ __forceinline__ void gl16(const void* g, void* l) {
    __builtin_amdgcn_global_load_lds(
        (const __attribute__((address_space(1))) unsigned*)g,
        (__attribute__((address_space(3))) unsigned*)l, 16, 0, 0);
}

// ---------------- CSR build ----------------

__global__ void k_hist(const int* __restrict__ src, int* __restrict__ cnt) {
    int e = blockIdx.x * blockDim.x + threadIdx.x;
    if (e < N_EDGES_C) atomicAdd(&cnt[src[e]], 1);
}

// phase 1: per-block reduce -> bsum[b]; fused: per-graph node histogram.
// shfl wave-reduce + one LDS step (was 10-barrier Hillis-Steele).
__global__ __launch_bounds__(1024)
void k_bsum(const int* __restrict__ cnt, int* __restrict__ bsum,
            const int* __restrict__ batch, int* __restrict__ gcnt) {
    __shared__ int wsum[16];
    __shared__ int h[NUM_GRAPHS_C];
    int tid = threadIdx.x;
    if (tid < NUM_GRAPHS_C) h[tid] = 0;
    __syncthreads();
    int i = blockIdx.x * 1024 + tid;
    int inb = (i < N_NODES_C);
    int v = inb ? cnt[i] : 0;
    if (inb) {
        int g = batch[i];
        if ((unsigned)g < NUM_GRAPHS_C) atomicAdd(&h[g], 1);
    }
    for (int ofs = 32; ofs > 0; ofs >>= 1) v += __shfl_down(v, ofs, 64);
    if ((tid & 63) == 0) wsum[tid >> 6] = v;
    __syncthreads();   // orders wsum writes AND h atomics before reads below
    if (tid < 16) {
        int w = wsum[tid];
        for (int ofs = 8; ofs > 0; ofs >>= 1) w += __shfl_down(w, ofs, 16);
        if (tid == 0) bsum[blockIdx.x] = w;
    }
    if (tid < NUM_GRAPHS_C && h[tid] > 0)
        atomicAdd(&gcnt[tid], h[tid]);
}

// phase 2 (fused bscan + apply): shfl wave-scan + one cross-wave LDS step
// (was 20-barrier Hillis-Steele).
__global__ __launch_bounds__(1024)
void k_scan_apply(const int* __restrict__ cnt, const int* __restrict__ bsum,
                  int* __restrict__ start, int* __restrict__ cursor) {
    __shared__ int wsum[16];
    __shared__ int bofs_s;
    const int tid = threadIdx.x;
    const int wid = tid >> 6, ln = tid & 63;
    // redundant per-block scan of the <=64 block sums -> this block's offset
    if (tid < 64) {
        int own = (tid < SCAN_NBLK) ? bsum[tid] : 0;
        int v = own;
        for (int ofs = 1; ofs < 64; ofs <<= 1) {
            int t = __shfl_up(v, ofs, 64);
            if (tid >= ofs) v += t;
        }
        if (tid == (int)blockIdx.x) bofs_s = v - own;          // exclusive
        if (blockIdx.x == 0 && tid == 63) start[N_NODES_C] = v; // grand total
    }
    int i = blockIdx.x * 1024 + tid;
    int v = (i < N_NODES_C) ? cnt[i] : 0;
    int s = v;  // wave-inclusive scan
    for (int ofs = 1; ofs < 64; ofs <<= 1) {
        int t = __shfl_up(s, ofs, 64);
        if (ln >= ofs) s += t;
    }
    if (ln == 63) wsum[wid] = s;
    __syncthreads();
    if (tid < 16) {
        int ws = wsum[tid];
        int sv = ws;
        for (int ofs = 1; ofs < 16; ofs <<= 1) {
            int t = __shfl_up(sv, ofs, 16);
            if (tid >= ofs) sv += t;
        }
        wsum[tid] = sv - ws;  // exclusive prefix of wave sums
    }
    __syncthreads();
    if (i < N_NODES_C) {
        int ex = bofs_s + wsum[wid] + s - v;
        start[i] = ex;
        cursor[i] = ex;
    }
}

__global__ void k_fill(const int* __restrict__ src, const int* __restrict__ dst,
                       int* __restrict__ cursor, int* __restrict__ ebuf) {
    int e = blockIdx.x * blockDim.x + threadIdx.x;
    if (e < N_EDGES_C) {
        int pos = atomicAdd(&cursor[src[e]], 1);
        ebuf[pos] = dst[e];
    }
}

// Weff[d,j] = sum_k sign[k,d] * Wp[k*128+col[k,d], j]   (fp32)
__global__ void k_weff(const float* __restrict__ Hm, const float* __restrict__ Wp,
                       float* __restrict__ Weff) {
    __shared__ int   scol[4];
    __shared__ float ssign[4];
    int d = blockIdx.x;
    int h = threadIdx.x;  // 128 threads
    for (int k = 0; k < 4; ++k) {
        float v = Hm[((size_t)k * DIM + d) * 128 + h];
        if (v != 0.0f) { scol[k] = h; ssign[k] = v; }
    }
    __syncthreads();
    for (int j = threadIdx.x; j < DIM; j += 128) {
        float acc = 0.0f;
#pragma unroll
        for (int k = 0; k < 4; ++k)
            acc += ssign[k] * Wp[(size_t)(k * 128 + scol[k]) * DIM + j];
        Weff[(size_t)d * DIM + j] = acc;
    }
}

// Wt[n][k] bf16, k-contiguous: k<512 -> Weff[k][n], k>=512 -> Ws[k-512][n]
__global__ void k_prepw(const float* __restrict__ Weff, const float* __restrict__ Ws,
                        short* __restrict__ Wt) {
    int n = blockIdx.x;
    for (int k = threadIdx.x; k < 2 * DIM; k += 256) {
        float v = (k < DIM) ? Weff[(size_t)k * DIM + n] : Ws[(size_t)(k - DIM) * DIM + n];
        Wt[(size_t)n * (2 * DIM) + k] = f2bf(v);
    }
}

// fp32 -> bf16 + fp8 shadow, 8 elems/thread
__global__ void k_cast(const float* __restrict__ x, short* __restrict__ xb,
                       unsigned char* __restrict__ xq) {
    int idx = blockIdx.x * blockDim.x + threadIdx.x;
    if (idx >= N_NODES_C * DIM / 8) return;
    const float* p = x + (size_t)idx * 8;
    float v[8];
    bf16x8 o;
#pragma unroll
    for (int j = 0; j < 8; ++j) { v[j] = p[j]; o[j] = f2bf(v[j]); }
    u32x2 q;
    q[0] = f32x4_to_fp8(v[0], v[1], v[2], v[3]);
    q[1] = f32x4_to_fp8(v[4], v[5], v[6], v[7]);
    *(bf16x8*)(xb + (size_t)idx * 8) = o;
    *(u32x2*)(xq + (size_t)idx * 8) = q;
}

// ---------------- aggregation: CSR gather (fp8 shadow) + mean/fallback ----------------
__global__ __launch_bounds__(256)
void k_gather_8(const unsigned char* __restrict__ Hq, const int* __restrict__ start,
                const int* __restrict__ ebuf, const short* __restrict__ fb,
                short* __restrict__ outb) {
    int n = blockIdx.x * 4 + (threadIdx.x >> 6);
    int l = threadIdx.x & 63;
    if (n >= N_NODES_C) return;
    int s = start[n], e = start[n + 1];
    float acc[8] = {0, 0, 0, 0, 0, 0, 0, 0};
    int i = s;
    if (i + 4 <= e) {
        int d0 = ebuf[i], d1 = ebuf[i + 1], d2 = ebuf[i + 2], d3 = ebuf[i + 3];
        for (; i + 8 <= e; i += 4) {
            int n0 = ebuf[i + 4], n1 = ebuf[i + 5], n2 = ebuf[i + 6], n3 = ebuf[i + 7];
            u32x2 w0 = *(const u32x2*)(Hq + (size_t)d0 * DIM + l * 8);
            u32x2 w1 = *(const u32x2*)(Hq + (size_t)d1 * DIM + l * 8);
            u32x2 w2 = *(const u32x2*)(Hq + (size_t)d2 * DIM + l * 8);
            u32x2 w3 = *(const u32x2*)(Hq + (size_t)d3 * DIM + l * 8);
            acc_fp8x8(acc, w0); acc_fp8x8(acc, w1);
            acc_fp8x8(acc, w2); acc_fp8x8(acc, w3);
            d0 = n0; d1 = n1; d2 = n2; d3 = n3;
        }
        {
            u32x2 w0 = *(const u32x2*)(Hq + (size_t)d0 * DIM + l * 8);
            u32x2 w1 = *(const u32x2*)(Hq + (size_t)d1 * DIM + l * 8);
            u32x2 w2 = *(const u32x2*)(Hq + (size_t)d2 * DIM + l * 8);
            u32x2 w3 = *(const u32x2*)(Hq + (size_t)d3 * DIM + l * 8);
            acc_fp8x8(acc, w0); acc_fp8x8(acc, w1);
            acc_fp8x8(acc, w2); acc_fp8x8(acc, w3);
            i += 4;
        }
    }
    for (; i < e; ++i) {
        int d0 = ebuf[i];
        u32x2 w0 = *(const u32x2*)(Hq + (size_t)d0 * DIM + l * 8);
        acc_fp8x8(acc, w0);
    }
    bf16x8 o;
    if (e > s) {
        float inv = 1.0f / (float)(e - s);
#pragma unroll
        for (int j = 0; j < 8; ++j) o[j] = f2bf(acc[j] * inv);
    } else {
        o = *(const bf16x8*)(fb + (size_t)n * DIM + l * 8);
    }
    *(bf16x8*)(outb + (size_t)n * DIM + l * 8) = o;
}

// ---------------- MFMA dual-GEMM ----------------
// 128x128 tile, BK=64, 4 waves, single-buffer (R2/R5 structure, proven).
// global_load_lds direct staging, XOR-swizzle on the pre-swizzled GLOBAL
// source (m173), linear LDS dest. MFMA operands SWAPPED: thread holds 4
// consecutive output COLUMNS of one row -> vectorized 8B bf16 + 4B fp8 stores.
// __launch_bounds__(256) PLAIN: the (256,4) hint capped occupancy at 4
// blocks/CU (occ 28.4%); plain compile measured VGPR=64 (R2) -> LDS-limited
// 5 blocks/CU (occ ~36%). NEVER use min-waves>=5: caps VGPR at 102 -> acc
// spills to scratch (R6: VGPR=48, WRITE_SIZE 3x, 215us).

__device__ __forceinline__ void gemm_core(const short* __restrict__ A1,
                                          const short* __restrict__ A2,
                                          const short* __restrict__ Wt,
                                          short* As, short* Bs,
                                          int row0, int col0,
                                          int wave, int lane, f32x4 (*acc)[4]) {
    const int wm = wave >> 1, wn = wave & 1;
    const int q = lane >> 4, t16 = lane & 15;
    const int rloc = wave * 32 + (lane >> 3);       // row within tile (+ j*8)
    const int csrc = (lane & 7) ^ (lane >> 3);      // pre-swizzled source chunk
    size_t aoff[4], boff[4];
#pragma unroll
    for (int j = 0; j < 4; ++j) {
        int grow = row0 + rloc + j * 8;
        if (grow >= N_NODES_C) grow = N_NODES_C - 1;   // clamp; masked in epilogue
        aoff[j] = (size_t)grow * DIM + csrc * 8;
        boff[j] = (size_t)(col0 + rloc + j * 8) * (2 * DIM) + csrc * 8;
    }
    short* AsW = As + wave * 2048;   // wave*32 rows * 64
    short* BsW = Bs + wave * 2048;
#pragma unroll
    for (int p = 0; p < 2; ++p) {
        const short* A = p ? A2 : A1;
        const short* W = Wt + p * DIM;
        for (int kt = 0; kt < DIM; kt += 64) {
            __syncthreads();  // previous round's LDS reads done before overwrite
#pragma unroll
            for (int j = 0; j < 4; ++j) {
                gl16(A + aoff[j] + kt, AsW + j * 512);
                gl16(W + boff[j] + kt, BsW + j * 512);
            }
            __syncthreads();  // compiler drains vmcnt(0) before this barrier
#pragma unroll
            for (int kh = 0; kh < 2; ++kh) {
                bf16x8 af[4], bfv[4];
#pragma unroll
                for (int mi = 0; mi < 4; ++mi) {
                    int r = wm * 64 + mi * 16 + t16;
                    int cp = (kh * 4 + q) ^ (t16 & 7);
                    af[mi] = *(const bf16x8*)(As + r * 64 + cp * 8);
                }
#pragma unroll
                for (int ni = 0; ni < 4; ++ni) {
                    int r = wn * 64 + ni * 16 + t16;
                    int cp = (kh * 4 + q) ^ (t16 & 7);
                    bfv[ni] = *(const bf16x8*)(Bs + r * 64 + cp * 8);
                }
                // swapped operands: D^T -> thread holds row = ..+t16,
                // cols = ..+q*4+r (4 consecutive) -> vector stores
#pragma unroll
                for (int mi = 0; mi < 4; ++mi)
#pragma unroll
                    for (int ni = 0; ni < 4; ++ni)
                        acc[mi][ni] = __builtin_amdgcn_mfma_f32_16x16x32_bf16(
                            bfv[ni], af[mi], acc[mi][ni], 0, 0, 0);
            }
        }
    }
}

__global__ __launch_bounds__(256)
void k_gemm_elu_mfma(const short* __restrict__ A1, const short* __restrict__ A2,
                     const short* __restrict__ Wt, const float* __restrict__ bias,
                     short* __restrict__ C, unsigned char* __restrict__ C8) {
    __shared__ __align__(16) short As[128 * 64];
    __shared__ __align__(16) short Bs[128 * 64];
    const int L = blockIdx.x;
    const int ct = (L & 31) >> 3;
    const int rt = ((L >> 5) << 3) + (L & 7);
    if (rt >= NROWT) return;
    const int row0 = rt * 128, col0 = ct * 128;
    const int tid = threadIdx.x;
    const int lane = tid & 63, wave = tid >> 6;
    const int wm = wave >> 1, wn = wave & 1;
    const int q = lane >> 4, t16 = lane & 15;
    f32x4 acc[4][4] = {};
    gemm_core(A1, A2, Wt, As, Bs, row0, col0, wave, lane, acc);
    // swapped layout: row = row0+wm*64+mi*16+t16; cols = col0+wn*64+ni*16+q*4+{0..3}
    f32x4 bv[4];
#pragma unroll
    for (int ni = 0; ni < 4; ++ni)
        bv[ni] = *(const f32x4*)(bias + col0 + wn * 64 + ni * 16 + q * 4);
#pragma unroll
    for (int mi = 0; mi < 4; ++mi) {
        int row = row0 + wm * 64 + mi * 16 + t16;
        if (row < N_NODES_C) {
#pragma unroll
            for (int ni = 0; ni < 4; ++ni) {
                int colq = col0 + wn * 64 + ni * 16 + q * 4;
                float v0 = eluf(acc[mi][ni][0] + bv[ni][0]);
                float v1 = eluf(acc[mi][ni][1] + bv[ni][1]);
                float v2 = eluf(acc[mi][ni][2] + bv[ni][2]);
                float v3 = eluf(acc[mi][ni][3] + bv[ni][3]);
                bf16x4 ob;
                ob[0] = f2bf(v0); ob[1] = f2bf(v1);
                ob[2] = f2bf(v2); ob[3] = f2bf(v3);
                *(bf16x4*)(C + (size_t)row * DIM + colq) = ob;
                *(unsigned*)(C8 + (size_t)row * DIM + colq) =
                    f32x4_to_fp8(v0, v1, v2, v3);
            }
        }
    }
}

__global__ __launch_bounds__(256)
void k_gemm_pool_mfma(const short* __restrict__ A1, const short* __restrict__ A2,
                      const short* __restrict__ Wt, const float* __restrict__ bias,
                      const int* __restrict__ batch, float* __restrict__ gsum) {
    __shared__ __align__(16) short As[128 * 64];
    __shared__ __align__(16) short Bs[128 * 64];
    const int L = blockIdx.x;
    const int ct = (L & 31) >> 3;
    const int rt = ((L >> 5) << 3) + (L & 7);
    if (rt >= NROWT) return;
    const int row0 = rt * 128, col0 = ct * 128;
    const int tid = threadIdx.x;
    const int lane = tid & 63, wave = tid >> 6;
    const int wm = wave >> 1, wn = wave & 1;
    const int q = lane >> 4, t16 = lane & 15;
    f32x4 acc[4][4] = {};
    gemm_core(A1, A2, Wt, As, Bs, row0, col0, wave, lane, acc);
    // batch loads direct from global (L2-broadcast). Rows OOB -> -1 sentinel.
    auto ldb = [&](int r) { return (r < N_NODES_C) ? batch[r] : -1; };
    f32x4 bv[4];
#pragma unroll
    for (int ni = 0; ni < 4; ++ni)
        bv[ni] = *(const f32x4*)(bias + col0 + wn * 64 + ni * 16 + q * 4);
    const int g0 = ldb(row0 + wm * 64);
    const int g63 = ldb(row0 + wm * 64 + 63);
    if (g0 == g63) {
        if (g0 >= 0) {
            // single graph for whole wave: per-thread col sums over 4 rows,
            // butterfly-reduce across the 16-lane t16 group, 16 atomics/wave
#pragma unroll
            for (int ni = 0; ni < 4; ++ni) {
#pragma unroll
                for (int r = 0; r < 4; ++r) {
                    float s = 0.0f;
#pragma unroll
                    for (int mi = 0; mi < 4; ++mi)
                        s += eluf(acc[mi][ni][r] + bv[ni][r]);
                    s += __shfl_xor(s, 1, 64);
                    s += __shfl_xor(s, 2, 64);
                    s += __shfl_xor(s, 4, 64);
                    s += __shfl_xor(s, 8, 64);
                    if (t16 == 0)
                        atomicAdd(&gsum[(size_t)g0 * DIM + col0 + wn * 64 +
                                        ni * 16 + q * 4 + r], s);
                }
            }
        }
    } else if (g0 >= 0) {
        // graph boundary inside wave (rare). batch is SORTED -> graphs in
        // this wave form the contiguous range [g0, gmx]. Loop over it with
        // graph-masked butterfly reduces: same conflict-free atomic pattern
        // as the fast path.
        int g_th[4];
#pragma unroll
        for (int mi = 0; mi < 4; ++mi) g_th[mi] = ldb(row0 + wm * 64 + mi * 16 + t16);
        int gmx = g0;
#pragma unroll
        for (int mi = 0; mi < 4; ++mi) gmx = max(gmx, g_th[mi]);
        gmx = max(gmx, __shfl_xor(gmx, 1, 64));
        gmx = max(gmx, __shfl_xor(gmx, 2, 64));
        gmx = max(gmx, __shfl_xor(gmx, 4, 64));
        gmx = max(gmx, __shfl_xor(gmx, 8, 64));   // wave-uniform max
        for (int gsel = g0; gsel <= gmx; ++gsel) {
#pragma unroll
            for (int ni = 0; ni < 4; ++ni) {
#pragma unroll
                for (int r = 0; r < 4; ++r) {
                    float s = 0.0f;
#pragma unroll
                    for (int mi = 0; mi < 4; ++mi) {
                        float v = eluf(acc[mi][ni][r] + bv[ni][r]);
                        s += (g_th[mi] == gsel) ? v : 0.0f;
                    }
                    s += __shfl_xor(s, 1, 64);
                    s += __shfl_xor(s, 2, 64);
                    s += __shfl_xor(s, 4, 64);
                    s += __shfl_xor(s, 8, 64);
                    if (t16 == 0)
                        atomicAdd(&gsum[(size_t)gsel * DIM + col0 + wn * 64 +
                                        ni * 16 + q * 4 + r], s);
                }
            }
        }
    }
}

// out[g,j] = (gsum[g,:]/max(cnt[g],1)) @ Wc[:,j] + bc[j]
__global__ void k_final(const float* __restrict__ gsum, const int* __restrict__ cnt,
                        const float* __restrict__ Wc, const float* __restrict__ bc,
                        float* __restrict__ out) {
    int g = blockIdx.x;
    int j = threadIdx.x;
    if (j >= NUM_CLASSES_C) return;
    int c_ = cnt[g];
    float inv = 1.0f / (float)(c_ > 1 ? c_ : 1);
    float s = 0.0f;
    for (int c = 0; c < DIM; ++c)
        s += gsum[(size_t)g * DIM + c] * Wc[(size_t)c * NUM_CLASSES_C + j];
    out[g * NUM_CLASSES_C + j] = s * inv + bc[j];
}

// ---------------- launch ----------------

extern "C" void kernel_launch(void* const* d_in, const int* in_sizes, int n_in,
                              void* d_out, int out_size, void* d_ws, size_t ws_size,
                              hipStream_t stream) {
    const float* x   = (const float*)d_in[0];
    const int*   ei  = (const int*)d_in[1];
    const int*   src = ei;
    const int*   dst = ei + N_EDGES_C;
    const int* batch = (const int*)d_in[2];
    const float* Hm1 = (const float*)d_in[3];
    const float* Wp1 = (const float*)d_in[4];
    const float* Ws1 = (const float*)d_in[5];
    const float* b1  = (const float*)d_in[6];
    const float* Hm2 = (const float*)d_in[7];
    const float* Wp2 = (const float*)d_in[8];
    const float* Ws2 = (const float*)d_in[9];
    const float* b2  = (const float*)d_in[10];
    const float* Wc  = (const float*)d_in[11];
    const float* bc  = (const float*)d_in[12];
    float* out = (float*)d_out;

    char* ws = (char*)d_ws;
    size_t off = 0;
    auto alloc = [&](size_t bytes) {
        void* p = ws + off;
        off += (bytes + 255) & ~(size_t)255;
        return p;
    };
    const size_t nodeB16 = (size_t)N_NODES_C * DIM * 2;  // 51.2 MB
    const size_t nodeB8  = (size_t)N_NODES_C * DIM;      // 25.6 MB
    short* xb    = (short*)alloc(nodeB16);
    short* aggB  = (short*)alloc(nodeB16);
    short* hB    = (short*)alloc(nodeB16);
    unsigned char* xq = (unsigned char*)alloc(nodeB8);   // fp8 shadow of x
    unsigned char* hq = (unsigned char*)alloc(nodeB8);   // fp8 shadow of h1
    float* Weff1 = (float*)alloc((size_t)DIM * DIM * 4);
    float* Weff2 = (float*)alloc((size_t)DIM * DIM * 4);
    short* Wt1   = (short*)alloc((size_t)DIM * 2 * DIM * 2);
    short* Wt2   = (short*)alloc((size_t)DIM * 2 * DIM * 2);
    int*   cnt_i = (int*)alloc((size_t)N_NODES_C * 4);
    int*   start = (int*)alloc((size_t)(N_NODES_C + 1) * 4);
    int*   cursor= (int*)alloc((size_t)N_NODES_C * 4);
    int*   ebuf  = (int*)alloc((size_t)N_EDGES_C * 4);
    int*   cnt   = (int*)alloc((size_t)NUM_GRAPHS_C * 4);
    float* gsum  = (float*)alloc((size_t)NUM_GRAPHS_C * DIM * 4);
    int*   bsum  = (int*)alloc((size_t)SCAN_NBLK * 4);

    hipMemsetAsync(cnt_i, 0, (size_t)N_NODES_C * 4, stream);
    hipMemsetAsync(cnt, 0, (size_t)NUM_GRAPHS_C * 4, stream);
    hipMemsetAsync(gsum, 0, (size_t)NUM_GRAPHS_C * DIM * 4, stream);

    // CSR build + weight prep + casts
    k_hist<<<(N_EDGES_C + 255) / 256, 256, 0, stream>>>(src, cnt_i);
    k_bsum<<<SCAN_NBLK, 1024, 0, stream>>>(cnt_i, bsum, batch, cnt);
    k_scan_apply<<<SCAN_NBLK, 1024, 0, stream>>>(cnt_i, bsum, start, cursor);
    k_fill<<<(N_EDGES_C + 255) / 256, 256, 0, stream>>>(src, dst, cursor, ebuf);
    k_weff<<<DIM, 128, 0, stream>>>(Hm1, Wp1, Weff1);
    k_weff<<<DIM, 128, 0, stream>>>(Hm2, Wp2, Weff2);
    k_prepw<<<DIM, 256, 0, stream>>>(Weff1, Ws1, Wt1);
    k_prepw<<<DIM, 256, 0, stream>>>(Weff2, Ws2, Wt2);
    k_cast<<<(N_NODES_C * DIM / 8 + 255) / 256, 256, 0, stream>>>(x, xb, xq);

    // layer 1
    k_gather_8<<<(N_NODES_C + 3) / 4, 256, 0, stream>>>(xq, start, ebuf, xb, aggB);
    k_gemm_elu_mfma<<<GEMM_BLOCKS, 256, 0, stream>>>(aggB, xb, Wt1, b1, hB, hq);

    // layer 2
    k_gather_8<<<(N_NODES_C + 3) / 4, 256, 0, stream>>>(hq, start, ebuf, hB, aggB);
    k_gemm_pool_mfma<<<GEMM_BLOCKS, 256, 0, stream>>>(aggB, hB, Wt2, b2, batch, gsum);

    k_final<<<NUM_GRAPHS_C, 64, 0, stream>>>(gsum, cnt, Wc, bc, out);
}

// Round 9
// 601.361 us; speedup vs baseline: 1.0502x; 1.0502x over previous
//
#include <hip/hip_runtime.h>
#include <hip/hip_bf16.h>
#include <math.h>

#define N_NODES_C 50000
#define N_EDGES_C 800000
#define DIM 512
#define NUM_GRAPHS_C 64
#define NUM_CLASSES_C 10

#define NROWT ((N_NODES_C + 127) / 128)              // 391 row-tiles
#define GEMM_BLOCKS (((NROWT * 4 + 31) / 32) * 32)   // 1568 (pad to swizzle group)

#define SCAN_BLK 1024
#define SCAN_NBLK ((N_NODES_C + SCAN_BLK - 1) / SCAN_BLK)  // 49 (<= 64)

typedef short bf16x8 __attribute__((ext_vector_type(8)));
typedef short bf16x4 __attribute__((ext_vector_type(4)));
typedef float f32x4 __attribute__((ext_vector_type(4)));
typedef float f32x2 __attribute__((ext_vector_type(2)));
typedef unsigned u32x2 __attribute__((ext_vector_type(2)));

__device__ __forceinline__ float bf2f(short s) {
    return __uint_as_float(((unsigned)(unsigned short)s) << 16);
}
__device__ __forceinline__ short f2bf(float f) {
    unsigned u = __float_as_uint(f);
    u += 0x7FFF + ((u >> 16) & 1);  // RNE
    return (short)(u >> 16);
}
// fast ELU: expf-1 instead of expm1f; abs err ~1e-7, invisible in bf16 out
__device__ __forceinline__ float eluf(float v) {
    return v > 0.0f ? v : __expf(v) - 1.0f;
}
__device__ __forceinline__ unsigned f32x4_to_fp8(float a, float b, float c, float d) {
    int w = 0;
    w = __builtin_amdgcn_cvt_pk_fp8_f32(a, b, w, false);
    w = __builtin_amdgcn_cvt_pk_fp8_f32(c, d, w, true);
    return (unsigned)w;
}
__device__ __forceinline__ void acc_fp8x8(float* acc, u32x2 w) {
    f32x2 a = __builtin_amdgcn_cvt_pk_f32_fp8((int)w[0], false);
    f32x2 b = __builtin_amdgcn_cvt_pk_f32_fp8((int)w[0], true);
    f32x2 c = __builtin_amdgcn_cvt_pk_f32_fp8((int)w[1], false);
    f32x2 d = __builtin_amdgcn_cvt_pk_f32_fp8((int)w[1], true);
    acc[0] += a[0]; acc[1] += a[1]; acc[2] += b[0]; acc[3] += b[1];
    acc[4] += c[0]; acc[5] += c[1]; acc[6] += d[0]; acc[7] += d[1];
}

// async global->LDS, 16B per lane; LDS dest = wave-uniform base + lane*16
__device__ __forceinline__ void gl16(const void* g, void* l) {
    __builtin_amdgcn_global_load_lds(
        (const __attribute__((address_space(1))) unsigned*)g,
        (__attribute__((address_space(3))) unsigned*)l, 16, 0, 0);
}

// ---------------- CSR build ----------------

__global__ void k_hist(const int* __restrict__ src, int* __restrict__ cnt) {
    int e = blockIdx.x * blockDim.x + threadIdx.x;
    if (e < N_EDGES_C) atomicAdd(&cnt[src[e]], 1);
}

// phase 1: per-block reduce -> bsum[b]; fused: per-graph node histogram.
__global__ __launch_bounds__(1024)
void k_bsum(const int* __restrict__ cnt, int* __restrict__ bsum,
            const int* __restrict__ batch, int* __restrict__ gcnt) {
    __shared__ int wsum[16];
    __shared__ int h[NUM_GRAPHS_C];
    int tid = threadIdx.x;
    if (tid < NUM_GRAPHS_C) h[tid] = 0;
    __syncthreads();
    int i = blockIdx.x * 1024 + tid;
    int inb = (i < N_NODES_C);
    int v = inb ? cnt[i] : 0;
    if (inb) {
        int g = batch[i];
        if ((unsigned)g < NUM_GRAPHS_C) atomicAdd(&h[g], 1);
    }
    for (int ofs = 32; ofs > 0; ofs >>= 1) v += __shfl_down(v, ofs, 64);
    if ((tid & 63) == 0) wsum[tid >> 6] = v;
    __syncthreads();   // orders wsum writes AND h atomics before reads below
    if (tid < 16) {
        int w = wsum[tid];
        for (int ofs = 8; ofs > 0; ofs >>= 1) w += __shfl_down(w, ofs, 16);
        if (tid == 0) bsum[blockIdx.x] = w;
    }
    if (tid < NUM_GRAPHS_C && h[tid] > 0)
        atomicAdd(&gcnt[tid], h[tid]);
}

// phase 2 (fused bscan + apply): shfl wave-scan + one cross-wave LDS step.
__global__ __launch_bounds__(1024)
void k_scan_apply(const int* __restrict__ cnt, const int* __restrict__ bsum,
                  int* __restrict__ start, int* __restrict__ cursor) {
    __shared__ int wsum[16];
    __shared__ int bofs_s;
    const int tid = threadIdx.x;
    const int wid = tid >> 6, ln = tid & 63;
    // redundant per-block scan of the <=64 block sums -> this block's offset
    if (tid < 64) {
        int own = (tid < SCAN_NBLK) ? bsum[tid] : 0;
        int v = own;
        for (int ofs = 1; ofs < 64; ofs <<= 1) {
            int t = __shfl_up(v, ofs, 64);
            if (tid >= ofs) v += t;
        }
        if (tid == (int)blockIdx.x) bofs_s = v - own;          // exclusive
        if (blockIdx.x == 0 && tid == 63) start[N_NODES_C] = v; // grand total
    }
    int i = blockIdx.x * 1024 + tid;
    int v = (i < N_NODES_C) ? cnt[i] : 0;
    int s = v;  // wave-inclusive scan
    for (int ofs = 1; ofs < 64; ofs <<= 1) {
        int t = __shfl_up(s, ofs, 64);
        if (ln >= ofs) s += t;
    }
    if (ln == 63) wsum[wid] = s;
    __syncthreads();
    if (tid < 16) {
        int ws = wsum[tid];
        int sv = ws;
        for (int ofs = 1; ofs < 16; ofs <<= 1) {
            int t = __shfl_up(sv, ofs, 16);
            if (tid >= ofs) sv += t;
        }
        wsum[tid] = sv - ws;  // exclusive prefix of wave sums
    }
    __syncthreads();
    if (i < N_NODES_C) {
        int ex = bofs_s + wsum[wid] + s - v;
        start[i] = ex;
        cursor[i] = ex;
    }
}

__global__ void k_fill(const int* __restrict__ src, const int* __restrict__ dst,
                       int* __restrict__ cursor, int* __restrict__ ebuf) {
    int e = blockIdx.x * blockDim.x + threadIdx.x;
    if (e < N_EDGES_C) {
        int pos = atomicAdd(&cursor[src[e]], 1);
        ebuf[pos] = dst[e];
    }
}

// Weff[d,j] = sum_k sign[k,d] * Wp[k*128+col[k,d], j]   (fp32)
__global__ void k_weff(const float* __restrict__ Hm, const float* __restrict__ Wp,
                       float* __restrict__ Weff) {
    __shared__ int   scol[4];
    __shared__ float ssign[4];
    int d = blockIdx.x;
    int h = threadIdx.x;  // 128 threads
    for (int k = 0; k < 4; ++k) {
        float v = Hm[((size_t)k * DIM + d) * 128 + h];
        if (v != 0.0f) { scol[k] = h; ssign[k] = v; }
    }
    __syncthreads();
    for (int j = threadIdx.x; j < DIM; j += 128) {
        float acc = 0.0f;
#pragma unroll
        for (int k = 0; k < 4; ++k)
            acc += ssign[k] * Wp[(size_t)(k * 128 + scol[k]) * DIM + j];
        Weff[(size_t)d * DIM + j] = acc;
    }
}

// Wt[n][k] bf16, k-contiguous: k<512 -> Weff[k][n], k>=512 -> Ws[k-512][n]
__global__ void k_prepw(const float* __restrict__ Weff, const float* __restrict__ Ws,
                        short* __restrict__ Wt) {
    int n = blockIdx.x;
    for (int k = threadIdx.x; k < 2 * DIM; k += 256) {
        float v = (k < DIM) ? Weff[(size_t)k * DIM + n] : Ws[(size_t)(k - DIM) * DIM + n];
        Wt[(size_t)n * (2 * DIM) + k] = f2bf(v);
    }
}

// fp32 -> bf16 + fp8 shadow, 8 elems/thread
__global__ void k_cast(const float* __restrict__ x, short* __restrict__ xb,
                       unsigned char* __restrict__ xq) {
    int idx = blockIdx.x * blockDim.x + threadIdx.x;
    if (idx >= N_NODES_C * DIM / 8) return;
    const float* p = x + (size_t)idx * 8;
    float v[8];
    bf16x8 o;
#pragma unroll
    for (int j = 0; j < 8; ++j) { v[j] = p[j]; o[j] = f2bf(v[j]); }
    u32x2 q;
    q[0] = f32x4_to_fp8(v[0], v[1], v[2], v[3]);
    q[1] = f32x4_to_fp8(v[4], v[5], v[6], v[7]);
    *(bf16x8*)(xb + (size_t)idx * 8) = o;
    *(u32x2*)(xq + (size_t)idx * 8) = q;
}

// ---------------- aggregation: CSR gather (fp8 shadow) + mean/fallback ----------------
// 8 row-loads in flight (was 4): gather is latency-bound on random 512B row
// reads; avg degree 16 -> 2 exposed-latency rounds instead of 4.
__global__ __launch_bounds__(256)
void k_gather_8(const unsigned char* __restrict__ Hq, const int* __restrict__ start,
                const int* __restrict__ ebuf, const short* __restrict__ fb,
                short* __restrict__ outb) {
    int n = blockIdx.x * 4 + (threadIdx.x >> 6);
    int l = threadIdx.x & 63;
    if (n >= N_NODES_C) return;
    int s = start[n], e = start[n + 1];
    float acc[8] = {0, 0, 0, 0, 0, 0, 0, 0};
    int i = s;
    for (; i + 8 <= e; i += 8) {
        u32x2 w[8];
#pragma unroll
        for (int t = 0; t < 8; ++t)
            w[t] = *(const u32x2*)(Hq + (size_t)ebuf[i + t] * DIM + l * 8);
#pragma unroll
        for (int t = 0; t < 8; ++t) acc_fp8x8(acc, w[t]);
    }
    if (i + 4 <= e) {
        u32x2 w[4];
#pragma unroll
        for (int t = 0; t < 4; ++t)
            w[t] = *(const u32x2*)(Hq + (size_t)ebuf[i + t] * DIM + l * 8);
#pragma unroll
        for (int t = 0; t < 4; ++t) acc_fp8x8(acc, w[t]);
        i += 4;
    }
    for (; i < e; ++i) {
        u32x2 w0 = *(const u32x2*)(Hq + (size_t)ebuf[i] * DIM + l * 8);
        acc_fp8x8(acc, w0);
    }
    bf16x8 o;
    if (e > s) {
        float inv = 1.0f / (float)(e - s);
#pragma unroll
        for (int j = 0; j < 8; ++j) o[j] = f2bf(acc[j] * inv);
    } else {
        o = *(const bf16x8*)(fb + (size_t)n * DIM + l * 8);
    }
    *(bf16x8*)(outb + (size_t)n * DIM + l * 8) = o;
}

// ---------------- MFMA dual-GEMM ----------------
// 128x128 tile, BK=64, 4 waves, single-buffer (R2/R5 structure, proven).
// global_load_lds direct staging, XOR-swizzle on the pre-swizzled GLOBAL
// source (m173), linear LDS dest. MFMA operands SWAPPED: thread holds 4
// consecutive output COLUMNS of one row -> vectorized 8B bf16 + 4B fp8 stores.
// __launch_bounds__(256,4) is the measured sweet spot: (256,5) caps VGPR at
// ~102 -> acc spills (R6: VGPR=48, 3x WRITE_SIZE, 215us); PLAIN lets the
// scheduler take 88 VGPR -> occupancy 17%, 100us (R8). (256,4) = 64 VGPR,
// 4 blocks/CU, 82us (R7). DO NOT change this attribute.

__device__ __forceinline__ void gemm_core(const short* __restrict__ A1,
                                          const short* __restrict__ A2,
                                          const short* __restrict__ Wt,
                                          short* As, short* Bs,
                                          int row0, int col0,
                                          int wave, int lane, f32x4 (*acc)[4]) {
    const int wm = wave >> 1, wn = wave & 1;
    const int q = lane >> 4, t16 = lane & 15;
    const int rloc = wave * 32 + (lane >> 3);       // row within tile (+ j*8)
    const int csrc = (lane & 7) ^ (lane >> 3);      // pre-swizzled source chunk
    size_t aoff[4], boff[4];
#pragma unroll
    for (int j = 0; j < 4; ++j) {
        int grow = row0 + rloc + j * 8;
        if (grow >= N_NODES_C) grow = N_NODES_C - 1;   // clamp; masked in epilogue
        aoff[j] = (size_t)grow * DIM + csrc * 8;
        boff[j] = (size_t)(col0 + rloc + j * 8) * (2 * DIM) + csrc * 8;
    }
    short* AsW = As + wave * 2048;   // wave*32 rows * 64
    short* BsW = Bs + wave * 2048;
#pragma unroll
    for (int p = 0; p < 2; ++p) {
        const short* A = p ? A2 : A1;
        const short* W = Wt + p * DIM;
        for (int kt = 0; kt < DIM; kt += 64) {
            __syncthreads();  // previous round's LDS reads done before overwrite
#pragma unroll
            for (int j = 0; j < 4; ++j) {
                gl16(A + aoff[j] + kt, AsW + j * 512);
                gl16(W + boff[j] + kt, BsW + j * 512);
            }
            __syncthreads();  // compiler drains vmcnt(0) before this barrier
#pragma unroll
            for (int kh = 0; kh < 2; ++kh) {
                bf16x8 af[4], bfv[4];
#pragma unroll
                for (int mi = 0; mi < 4; ++mi) {
                    int r = wm * 64 + mi * 16 + t16;
                    int cp = (kh * 4 + q) ^ (t16 & 7);
                    af[mi] = *(const bf16x8*)(As + r * 64 + cp * 8);
                }
#pragma unroll
                for (int ni = 0; ni < 4; ++ni) {
                    int r = wn * 64 + ni * 16 + t16;
                    int cp = (kh * 4 + q) ^ (t16 & 7);
                    bfv[ni] = *(const bf16x8*)(Bs + r * 64 + cp * 8);
                }
                // swapped operands: D^T -> thread holds row = ..+t16,
                // cols = ..+q*4+r (4 consecutive) -> vector stores
#pragma unroll
                for (int mi = 0; mi < 4; ++mi)
#pragma unroll
                    for (int ni = 0; ni < 4; ++ni)
                        acc[mi][ni] = __builtin_amdgcn_mfma_f32_16x16x32_bf16(
                            bfv[ni], af[mi], acc[mi][ni], 0, 0, 0);
            }
        }
    }
}

__global__ __launch_bounds__(256, 4)
void k_gemm_elu_mfma(const short* __restrict__ A1, const short* __restrict__ A2,
                     const short* __restrict__ Wt, const float* __restrict__ bias,
                     short* __restrict__ C, unsigned char* __restrict__ C8) {
    __shared__ __align__(16) short As[128 * 64];
    __shared__ __align__(16) short Bs[128 * 64];
    const int L = blockIdx.x;
    const int ct = (L & 31) >> 3;
    const int rt = ((L >> 5) << 3) + (L & 7);
    if (rt >= NROWT) return;
    const int row0 = rt * 128, col0 = ct * 128;
    const int tid = threadIdx.x;
    const int lane = tid & 63, wave = tid >> 6;
    const int wm = wave >> 1, wn = wave & 1;
    const int q = lane >> 4, t16 = lane & 15;
    f32x4 acc[4][4] = {};
    gemm_core(A1, A2, Wt, As, Bs, row0, col0, wave, lane, acc);
    // swapped layout: row = row0+wm*64+mi*16+t16; cols = col0+wn*64+ni*16+q*4+{0..3}
    f32x4 bv[4];
#pragma unroll
    for (int ni = 0; ni < 4; ++ni)
        bv[ni] = *(const f32x4*)(bias + col0 + wn * 64 + ni * 16 + q * 4);
#pragma unroll
    for (int mi = 0; mi < 4; ++mi) {
        int row = row0 + wm * 64 + mi * 16 + t16;
        if (row < N_NODES_C) {
#pragma unroll
            for (int ni = 0; ni < 4; ++ni) {
                int colq = col0 + wn * 64 + ni * 16 + q * 4;
                float v0 = eluf(acc[mi][ni][0] + bv[ni][0]);
                float v1 = eluf(acc[mi][ni][1] + bv[ni][1]);
                float v2 = eluf(acc[mi][ni][2] + bv[ni][2]);
                float v3 = eluf(acc[mi][ni][3] + bv[ni][3]);
                bf16x4 ob;
                ob[0] = f2bf(v0); ob[1] = f2bf(v1);
                ob[2] = f2bf(v2); ob[3] = f2bf(v3);
                *(bf16x4*)(C + (size_t)row * DIM + colq) = ob;
                *(unsigned*)(C8 + (size_t)row * DIM + colq) =
                    f32x4_to_fp8(v0, v1, v2, v3);
            }
        }
    }
}

__global__ __launch_bounds__(256, 4)
void k_gemm_pool_mfma(const short* __restrict__ A1, const short* __restrict__ A2,
                      const short* __restrict__ Wt, const float* __restrict__ bias,
                      const int* __restrict__ batch, float* __restrict__ gsum) {
    __shared__ __align__(16) short As[128 * 64];
    __shared__ __align__(16) short Bs[128 * 64];
    const int L = blockIdx.x;
    const int ct = (L & 31) >> 3;
    const int rt = ((L >> 5) << 3) + (L & 7);
    if (rt >= NROWT) return;
    const int row0 = rt * 128, col0 = ct * 128;
    const int tid = threadIdx.x;
    const int lane = tid & 63, wave = tid >> 6;
    const int wm = wave >> 1, wn = wave & 1;
    const int q = lane >> 4, t16 = lane & 15;
    f32x4 acc[4][4] = {};
    gemm_core(A1, A2, Wt, As, Bs, row0, col0, wave, lane, acc);
    // batch loads direct from global (L2-broadcast). Rows OOB -> -1 sentinel.
    auto ldb = [&](int r) { return (r < N_NODES_C) ? batch[r] : -1; };
    f32x4 bv[4];
#pragma unroll
    for (int ni = 0; ni < 4; ++ni)
        bv[ni] = *(const f32x4*)(bias + col0 + wn * 64 + ni * 16 + q * 4);
    const int g0 = ldb(row0 + wm * 64);
    const int g63 = ldb(row0 + wm * 64 + 63);
    if (g0 == g63) {
        if (g0 >= 0) {
            // single graph for whole wave: per-thread col sums over 4 rows,
            // butterfly-reduce across the 16-lane t16 group, 16 atomics/wave
#pragma unroll
            for (int ni = 0; ni < 4; ++ni) {
#pragma unroll
                for (int r = 0; r < 4; ++r) {
                    float s = 0.0f;
#pragma unroll
                    for (int mi = 0; mi < 4; ++mi)
                        s += eluf(acc[mi][ni][r] + bv[ni][r]);
                    s += __shfl_xor(s, 1, 64);
                    s += __shfl_xor(s, 2, 64);
                    s += __shfl_xor(s, 4, 64);
                    s += __shfl_xor(s, 8, 64);
                    if (t16 == 0)
                        atomicAdd(&gsum[(size_t)g0 * DIM + col0 + wn * 64 +
                                        ni * 16 + q * 4 + r], s);
                }
            }
        }
    } else if (g0 >= 0) {
        // graph boundary inside wave (rare). batch is SORTED -> graphs in
        // this wave form the contiguous range [g0, gmx]. Loop over it with
        // graph-masked butterfly reduces: same conflict-free atomic pattern
        // as the fast path.
        int g_th[4];
#pragma unroll
        for (int mi = 0; mi < 4; ++mi) g_th[mi] = ldb(row0 + wm * 64 + mi * 16 + t16);
        int gmx = g0;
#pragma unroll
        for (int mi = 0; mi < 4; ++mi) gmx = max(gmx, g_th[mi]);
        gmx = max(gmx, __shfl_xor(gmx, 1, 64));
        gmx = max(gmx, __shfl_xor(gmx, 2, 64));
        gmx = max(gmx, __shfl_xor(gmx, 4, 64));
        gmx = max(gmx, __shfl_xor(gmx, 8, 64));   // wave-uniform max
        for (int gsel = g0; gsel <= gmx; ++gsel) {
#pragma unroll
            for (int ni = 0; ni < 4; ++ni) {
#pragma unroll
                for (int r = 0; r < 4; ++r) {
                    float s = 0.0f;
#pragma unroll
                    for (int mi = 0; mi < 4; ++mi) {
                        float v = eluf(acc[mi][ni][r] + bv[ni][r]);
                        s += (g_th[mi] == gsel) ? v : 0.0f;
                    }
                    s += __shfl_xor(s, 1, 64);
                    s += __shfl_xor(s, 2, 64);
                    s += __shfl_xor(s, 4, 64);
                    s += __shfl_xor(s, 8, 64);
                    if (t16 == 0)
                        atomicAdd(&gsum[(size_t)gsel * DIM + col0 + wn * 64 +
                                        ni * 16 + q * 4 + r], s);
                }
            }
        }
    }
}

// out[g,j] = (gsum[g,:]/max(cnt[g],1)) @ Wc[:,j] + bc[j]
__global__ void k_final(const float* __restrict__ gsum, const int* __restrict__ cnt,
                        const float* __restrict__ Wc, const float* __restrict__ bc,
                        float* __restrict__ out) {
    int g = blockIdx.x;
    int j = threadIdx.x;
    if (j >= NUM_CLASSES_C) return;
    int c_ = cnt[g];
    float inv = 1.0f / (float)(c_ > 1 ? c_ : 1);
    float s = 0.0f;
    for (int c = 0; c < DIM; ++c)
        s += gsum[(size_t)g * DIM + c] * Wc[(size_t)c * NUM_CLASSES_C + j];
    out[g * NUM_CLASSES_C + j] = s * inv + bc[j];
}

// ---------------- launch ----------------

extern "C" void kernel_launch(void* const* d_in, const int* in_sizes, int n_in,
                              void* d_out, int out_size, void* d_ws, size_t ws_size,
                              hipStream_t stream) {
    const float* x   = (const float*)d_in[0];
    const int*   ei  = (const int*)d_in[1];
    const int*   src = ei;
    const int*   dst = ei + N_EDGES_C;
    const int* batch = (const int*)d_in[2];
    const float* Hm1 = (const float*)d_in[3];
    const float* Wp1 = (const float*)d_in[4];
    const float* Ws1 = (const float*)d_in[5];
    const float* b1  = (const float*)d_in[6];
    const float* Hm2 = (const float*)d_in[7];
    const float* Wp2 = (const float*)d_in[8];
    const float* Ws2 = (const float*)d_in[9];
    const float* b2  = (const float*)d_in[10];
    const float* Wc  = (const float*)d_in[11];
    const float* bc  = (const float*)d_in[12];
    float* out = (float*)d_out;

    char* ws = (char*)d_ws;
    size_t off = 0;
    auto alloc = [&](size_t bytes) {
        void* p = ws + off;
        off += (bytes + 255) & ~(size_t)255;
        return p;
    };
    const size_t nodeB16 = (size_t)N_NODES_C * DIM * 2;  // 51.2 MB
    const size_t nodeB8  = (size_t)N_NODES_C * DIM;      // 25.6 MB
    short* xb    = (short*)alloc(nodeB16);
    short* aggB  = (short*)alloc(nodeB16);
    short* hB    = (short*)alloc(nodeB16);
    unsigned char* xq = (unsigned char*)alloc(nodeB8);   // fp8 shadow of x
    unsigned char* hq = (unsigned char*)alloc(nodeB8);   // fp8 shadow of h1
    float* Weff1 = (float*)alloc((size_t)DIM * DIM * 4);
    float* Weff2 = (float*)alloc((size_t)DIM * DIM * 4);
    short* Wt1   = (short*)alloc((size_t)DIM * 2 * DIM * 2);
    short* Wt2   = (short*)alloc((size_t)DIM * 2 * DIM * 2);
    int*   cnt_i = (int*)alloc((size_t)N_NODES_C * 4);
    int*   start = (int*)alloc((size_t)(N_NODES_C + 1) * 4);
    int*   cursor= (int*)alloc((size_t)N_NODES_C * 4);
    int*   ebuf  = (int*)alloc((size_t)N_EDGES_C * 4);
    int*   cnt   = (int*)alloc((size_t)NUM_GRAPHS_C * 4);
    float* gsum  = (float*)alloc((size_t)NUM_GRAPHS_C * DIM * 4);
    int*   bsum  = (int*)alloc((size_t)SCAN_NBLK * 4);

    hipMemsetAsync(cnt_i, 0, (size_t)N_NODES_C * 4, stream);
    hipMemsetAsync(cnt, 0, (size_t)NUM_GRAPHS_C * 4, stream);
    hipMemsetAsync(gsum, 0, (size_t)NUM_GRAPHS_C * DIM * 4, stream);

    // CSR build + weight prep + casts
    k_hist<<<(N_EDGES_C + 255) / 256, 256, 0, stream>>>(src, cnt_i);
    k_bsum<<<SCAN_NBLK, 1024, 0, stream>>>(cnt_i, bsum, batch, cnt);
    k_scan_apply<<<SCAN_NBLK, 1024, 0, stream>>>(cnt_i, bsum, start, cursor);
    k_fill<<<(N_EDGES_C + 255) / 256, 256, 0, stream>>>(src, dst, cursor, ebuf);
    k_weff<<<DIM, 128, 0, stream>>>(Hm1, Wp1, Weff1);
    k_weff<<<DIM, 128, 0, stream>>>(Hm2, Wp2, Weff2);
    k_prepw<<<DIM, 256, 0, stream>>>(Weff1, Ws1, Wt1);
    k_prepw<<<DIM, 256, 0, stream>>>(Weff2, Ws2, Wt2);
    k_cast<<<(N_NODES_C * DIM / 8 + 255) / 256, 256, 0, stream>>>(x, xb, xq);

    // layer 1
    k_gather_8<<<(N_NODES_C + 3) / 4, 256, 0, stream>>>(xq, start, ebuf, xb, aggB);
    k_gemm_elu_mfma<<<GEMM_BLOCKS, 256, 0, stream>>>(aggB, xb, Wt1, b1, hB, hq);

    // layer 2
    k_gather_8<<<(N_NODES_C + 3) / 4, 256, 0, stream>>>(hq, start, ebuf, hB, aggB);
    k_gemm_pool_mfma<<<GEMM_BLOCKS, 256, 0, stream>>>(aggB, hB, Wt2, b2, batch, gsum);

    k_final<<<NUM_GRAPHS_C, 64, 0, stream>>>(gsum, cnt, Wc, bc, out);
}

// Round 10
// 567.068 us; speedup vs baseline: 1.1137x; 1.0605x over previous
//
#include <hip/hip_runtime.h>
#include <hip/hip_bf16.h>
#include <math.h>

#define N_NODES_C 50000
#define N_EDGES_C 800000
#define DIM 512
#define NUM_GRAPHS_C 64
#define NUM_CLASSES_C 10

#define NROWT ((N_NODES_C + 127) / 128)              // 391 row-tiles
#define GEMM_BLOCKS (((NROWT * 4 + 31) / 32) * 32)   // 1568 (pad to swizzle group)

#define SCAN_BLK 1024
#define SCAN_NBLK ((N_NODES_C + SCAN_BLK - 1) / SCAN_BLK)  // 49 (<= 64)

typedef short bf16x8 __attribute__((ext_vector_type(8)));
typedef short bf16x4 __attribute__((ext_vector_type(4)));
typedef float f32x4 __attribute__((ext_vector_type(4)));
typedef float f32x2 __attribute__((ext_vector_type(2)));
typedef unsigned u32x2 __attribute__((ext_vector_type(2)));

__device__ __forceinline__ float bf2f(short s) {
    return __uint_as_float(((unsigned)(unsigned short)s) << 16);
}
__device__ __forceinline__ short f2bf(float f) {
    unsigned u = __float_as_uint(f);
    u += 0x7FFF + ((u >> 16) & 1);  // RNE
    return (short)(u >> 16);
}
// fast ELU: expf-1 instead of expm1f; abs err ~1e-7, invisible in bf16 out
__device__ __forceinline__ float eluf(float v) {
    return v > 0.0f ? v : __expf(v) - 1.0f;
}
__device__ __forceinline__ unsigned f32x4_to_fp8(float a, float b, float c, float d) {
    int w = 0;
    w = __builtin_amdgcn_cvt_pk_fp8_f32(a, b, w, false);
    w = __builtin_amdgcn_cvt_pk_fp8_f32(c, d, w, true);
    return (unsigned)w;
}
__device__ __forceinline__ void acc_fp8x8(float* acc, u32x2 w) {
    f32x2 a = __builtin_amdgcn_cvt_pk_f32_fp8((int)w[0], false);
    f32x2 b = __builtin_amdgcn_cvt_pk_f32_fp8((int)w[0], true);
    f32x2 c = __builtin_amdgcn_cvt_pk_f32_fp8((int)w[1], false);
    f32x2 d = __builtin_amdgcn_cvt_pk_f32_fp8((int)w[1], true);
    acc[0] += a[0]; acc[1] += a[1]; acc[2] += b[0]; acc[3] += b[1];
    acc[4] += c[0]; acc[5] += c[1]; acc[6] += d[0]; acc[7] += d[1];
}

// async global->LDS, 16B per lane; LDS dest = wave-uniform base + lane*16
__device__ __forceinline__ void gl16(const void* g, void* l) {
    __builtin_amdgcn_global_load_lds(
        (const __attribute__((address_space(1))) unsigned*)g,
        (__attribute__((address_space(3))) unsigned*)l, 16, 0, 0);
}

// ---------------- CSR build ----------------

__global__ void k_hist(const int* __restrict__ src, int* __restrict__ cnt) {
    int e = blockIdx.x * blockDim.x + threadIdx.x;
    if (e < N_EDGES_C) atomicAdd(&cnt[src[e]], 1);
}

// phase 1: per-block reduce -> bsum[b]; fused: per-graph node histogram.
__global__ __launch_bounds__(1024)
void k_bsum(const int* __restrict__ cnt, int* __restrict__ bsum,
            const int* __restrict__ batch, int* __restrict__ gcnt) {
    __shared__ int wsum[16];
    __shared__ int h[NUM_GRAPHS_C];
    int tid = threadIdx.x;
    if (tid < NUM_GRAPHS_C) h[tid] = 0;
    __syncthreads();
    int i = blockIdx.x * 1024 + tid;
    int inb = (i < N_NODES_C);
    int v = inb ? cnt[i] : 0;
    if (inb) {
        int g = batch[i];
        if ((unsigned)g < NUM_GRAPHS_C) atomicAdd(&h[g], 1);
    }
    for (int ofs = 32; ofs > 0; ofs >>= 1) v += __shfl_down(v, ofs, 64);
    if ((tid & 63) == 0) wsum[tid >> 6] = v;
    __syncthreads();   // orders wsum writes AND h atomics before reads below
    if (tid < 16) {
        int w = wsum[tid];
        for (int ofs = 8; ofs > 0; ofs >>= 1) w += __shfl_down(w, ofs, 16);
        if (tid == 0) bsum[blockIdx.x] = w;
    }
    if (tid < NUM_GRAPHS_C && h[tid] > 0)
        atomicAdd(&gcnt[tid], h[tid]);
}

// phase 2 (fused bscan + apply): shfl wave-scan + one cross-wave LDS step.
__global__ __launch_bounds__(1024)
void k_scan_apply(const int* __restrict__ cnt, const int* __restrict__ bsum,
                  int* __restrict__ start, int* __restrict__ cursor) {
    __shared__ int wsum[16];
    __shared__ int bofs_s;
    const int tid = threadIdx.x;
    const int wid = tid >> 6, ln = tid & 63;
    // redundant per-block scan of the <=64 block sums -> this block's offset
    if (tid < 64) {
        int own = (tid < SCAN_NBLK) ? bsum[tid] : 0;
        int v = own;
        for (int ofs = 1; ofs < 64; ofs <<= 1) {
            int t = __shfl_up(v, ofs, 64);
            if (tid >= ofs) v += t;
        }
        if (tid == (int)blockIdx.x) bofs_s = v - own;          // exclusive
        if (blockIdx.x == 0 && tid == 63) start[N_NODES_C] = v; // grand total
    }
    int i = blockIdx.x * 1024 + tid;
    int v = (i < N_NODES_C) ? cnt[i] : 0;
    int s = v;  // wave-inclusive scan
    for (int ofs = 1; ofs < 64; ofs <<= 1) {
        int t = __shfl_up(s, ofs, 64);
        if (ln >= ofs) s += t;
    }
    if (ln == 63) wsum[wid] = s;
    __syncthreads();
    if (tid < 16) {
        int ws = wsum[tid];
        int sv = ws;
        for (int ofs = 1; ofs < 16; ofs <<= 1) {
            int t = __shfl_up(sv, ofs, 16);
            if (tid >= ofs) sv += t;
        }
        wsum[tid] = sv - ws;  // exclusive prefix of wave sums
    }
    __syncthreads();
    if (i < N_NODES_C) {
        int ex = bofs_s + wsum[wid] + s - v;
        start[i] = ex;
        cursor[i] = ex;
    }
}

__global__ void k_fill(const int* __restrict__ src, const int* __restrict__ dst,
                       int* __restrict__ cursor, int* __restrict__ ebuf) {
    int e = blockIdx.x * blockDim.x + threadIdx.x;
    if (e < N_EDGES_C) {
        int pos = atomicAdd(&cursor[src[e]], 1);
        ebuf[pos] = dst[e];
    }
}

// Weff[d,j] = sum_k sign[k,d] * Wp[k*128+col[k,d], j]   (fp32)
__global__ void k_weff(const float* __restrict__ Hm, const float* __restrict__ Wp,
                       float* __restrict__ Weff) {
    __shared__ int   scol[4];
    __shared__ float ssign[4];
    int d = blockIdx.x;
    int h = threadIdx.x;  // 128 threads
    for (int k = 0; k < 4; ++k) {
        float v = Hm[((size_t)k * DIM + d) * 128 + h];
        if (v != 0.0f) { scol[k] = h; ssign[k] = v; }
    }
    __syncthreads();
    for (int j = threadIdx.x; j < DIM; j += 128) {
        float acc = 0.0f;
#pragma unroll
        for (int k = 0; k < 4; ++k)
            acc += ssign[k] * Wp[(size_t)(k * 128 + scol[k]) * DIM + j];
        Weff[(size_t)d * DIM + j] = acc;
    }
}

// Wt[n][k] bf16, k-contiguous: k<512 -> Weff[k][n], k>=512 -> Ws[k-512][n].
// LDS-tiled 64x64 transpose: old version read Weff/Ws column-wise at
// stride 2KB (one 64B line per 4B load, ~64MB effective traffic); now both
// read (along n) and write (along k) are coalesced. +1-pad row (65 floats)
// -> phase-B LDS reads hit banks (tk+no)&31: conflict-free.
__global__ __launch_bounds__(256)
void k_prepw(const float* __restrict__ Weff, const float* __restrict__ Ws,
             short* __restrict__ Wt) {
    __shared__ float lds[64][65];
    const int bx = blockIdx.x;          // 8 n-tiles x 16 k-tiles = 128 blocks
    const int n0 = (bx & 7) * 64;
    const int k0 = (bx >> 3) * 64;
    const int t = threadIdx.x;
    const int tl = t & 63, tq = t >> 6;  // lane-in-64, quarter 0..3
    // uniform per block: k-tile entirely in Weff or entirely in Ws
    const float* S = (k0 < DIM) ? (Weff + (size_t)k0 * DIM)
                                : (Ws + (size_t)(k0 - DIM) * DIM);
    for (int ko = tq; ko < 64; ko += 4)
        lds[ko][tl] = S[(size_t)ko * DIM + n0 + tl];
    __syncthreads();
    for (int no = tq; no < 64; no += 4)
        Wt[(size_t)(n0 + no) * (2 * DIM) + k0 + tl] = f2bf(lds[tl][no]);
}

// fp32 -> bf16 + fp8 shadow, 8 elems/thread
__global__ void k_cast(const float* __restrict__ x, short* __restrict__ xb,
                       unsigned char* __restrict__ xq) {
    int idx = blockIdx.x * blockDim.x + threadIdx.x;
    if (idx >= N_NODES_C * DIM / 8) return;
    const float* p = x + (size_t)idx * 8;
    float v[8];
    bf16x8 o;
#pragma unroll
    for (int j = 0; j < 8; ++j) { v[j] = p[j]; o[j] = f2bf(v[j]); }
    u32x2 q;
    q[0] = f32x4_to_fp8(v[0], v[1], v[2], v[3]);
    q[1] = f32x4_to_fp8(v[4], v[5], v[6], v[7]);
    *(bf16x8*)(xb + (size_t)idx * 8) = o;
    *(u32x2*)(xq + (size_t)idx * 8) = q;
}

// ---------------- aggregation: CSR gather (fp8 shadow) + mean/fallback ----------------
// 8 row-loads in flight: gather is latency-bound on random 512B row reads.
__global__ __launch_bounds__(256)
void k_gather_8(const unsigned char* __restrict__ Hq, const int* __restrict__ start,
                const int* __restrict__ ebuf, const short* __restrict__ fb,
                short* __restrict__ outb) {
    int n = blockIdx.x * 4 + (threadIdx.x >> 6);
    int l = threadIdx.x & 63;
    if (n >= N_NODES_C) return;
    int s = start[n], e = start[n + 1];
    float acc[8] = {0, 0, 0, 0, 0, 0, 0, 0};
    int i = s;
    for (; i + 8 <= e; i += 8) {
        u32x2 w[8];
#pragma unroll
        for (int t = 0; t < 8; ++t)
            w[t] = *(const u32x2*)(Hq + (size_t)ebuf[i + t] * DIM + l * 8);
#pragma unroll
        for (int t = 0; t < 8; ++t) acc_fp8x8(acc, w[t]);
    }
    if (i + 4 <= e) {
        u32x2 w[4];
#pragma unroll
        for (int t = 0; t < 4; ++t)
            w[t] = *(const u32x2*)(Hq + (size_t)ebuf[i + t] * DIM + l * 8);
#pragma unroll
        for (int t = 0; t < 4; ++t) acc_fp8x8(acc, w[t]);
        i += 4;
    }
    for (; i < e; ++i) {
        u32x2 w0 = *(const u32x2*)(Hq + (size_t)ebuf[i] * DIM + l * 8);
        acc_fp8x8(acc, w0);
    }
    bf16x8 o;
    if (e > s) {
        float inv = 1.0f / (float)(e - s);
#pragma unroll
        for (int j = 0; j < 8; ++j) o[j] = f2bf(acc[j] * inv);
    } else {
        o = *(const bf16x8*)(fb + (size_t)n * DIM + l * 8);
    }
    *(bf16x8*)(outb + (size_t)n * DIM + l * 8) = o;
}

// ---------------- MFMA dual-GEMM ----------------
// 128x128 tile, BK=64, 4 waves, single-buffer (R2/R5 structure, proven).
// global_load_lds direct staging, XOR-swizzle on the pre-swizzled GLOBAL
// source (m173), linear LDS dest. MFMA operands SWAPPED: thread holds 4
// consecutive output COLUMNS of one row -> vectorized 8B bf16 + 4B fp8 stores.
// __launch_bounds__(256,4) is the measured sweet spot: (256,5) caps VGPR at
// ~102 -> acc spills (R6: VGPR=48, 3x WRITE_SIZE, 215us); PLAIN lets the
// scheduler take 88 VGPR -> occupancy 17%, 100us (R8). (256,4) = 64 VGPR,
// 4 blocks/CU, 82us (R7/R9). DO NOT change this attribute.

__device__ __forceinline__ void gemm_core(const short* __restrict__ A1,
                                          const short* __restrict__ A2,
                                          const short* __restrict__ Wt,
                                          short* As, short* Bs,
                                          int row0, int col0,
                                          int wave, int lane, f32x4 (*acc)[4]) {
    const int wm = wave >> 1, wn = wave & 1;
    const int q = lane >> 4, t16 = lane & 15;
    const int rloc = wave * 32 + (lane >> 3);       // row within tile (+ j*8)
    const int csrc = (lane & 7) ^ (lane >> 3);      // pre-swizzled source chunk
    size_t aoff[4], boff[4];
#pragma unroll
    for (int j = 0; j < 4; ++j) {
        int grow = row0 + rloc + j * 8;
        if (grow >= N_NODES_C) grow = N_NODES_C - 1;   // clamp; masked in epilogue
        aoff[j] = (size_t)grow * DIM + csrc * 8;
        boff[j] = (size_t)(col0 + rloc + j * 8) * (2 * DIM) + csrc * 8;
    }
    short* AsW = As + wave * 2048;   // wave*32 rows * 64
    short* BsW = Bs + wave * 2048;
#pragma unroll
    for (int p = 0; p < 2; ++p) {
        const short* A = p ? A2 : A1;
        const short* W = Wt + p * DIM;
        for (int kt = 0; kt < DIM; kt += 64) {
            __syncthreads();  // previous round's LDS reads done before overwrite
#pragma unroll
            for (int j = 0; j < 4; ++j) {
                gl16(A + aoff[j] + kt, AsW + j * 512);
                gl16(W + boff[j] + kt, BsW + j * 512);
            }
            __syncthreads();  // compiler drains vmcnt(0) before this barrier
#pragma unroll
            for (int kh = 0; kh < 2; ++kh) {
                bf16x8 af[4], bfv[4];
#pragma unroll
                for (int mi = 0; mi < 4; ++mi) {
                    int r = wm * 64 + mi * 16 + t16;
                    int cp = (kh * 4 + q) ^ (t16 & 7);
                    af[mi] = *(const bf16x8*)(As + r * 64 + cp * 8);
                }
#pragma unroll
                for (int ni = 0; ni < 4; ++ni) {
                    int r = wn * 64 + ni * 16 + t16;
                    int cp = (kh * 4 + q) ^ (t16 & 7);
                    bfv[ni] = *(const bf16x8*)(Bs + r * 64 + cp * 8);
                }
                // swapped operands: D^T -> thread holds row = ..+t16,
                // cols = ..+q*4+r (4 consecutive) -> vector stores
#pragma unroll
                for (int mi = 0; mi < 4; ++mi)
#pragma unroll
                    for (int ni = 0; ni < 4; ++ni)
                        acc[mi][ni] = __builtin_amdgcn_mfma_f32_16x16x32_bf16(
                            bfv[ni], af[mi], acc[mi][ni], 0, 0, 0);
            }
        }
    }
}

__global__ __launch_bounds__(256, 4)
void k_gemm_elu_mfma(const short* __restrict__ A1, const short* __restrict__ A2,
                     const short* __restrict__ Wt, const float* __restrict__ bias,
                     short* __restrict__ C, unsigned char* __restrict__ C8) {
    __shared__ __align__(16) short As[128 * 64];
    __shared__ __align__(16) short Bs[128 * 64];
    const int L = blockIdx.x;
    const int ct = (L & 31) >> 3;
    const int rt = ((L >> 5) << 3) + (L & 7);
    if (rt >= NROWT) return;
    const int row0 = rt * 128, col0 = ct * 128;
    const int tid = threadIdx.x;
    const int lane = tid & 63, wave = tid >> 6;
    const int wm = wave >> 1, wn = wave & 1;
    const int q = lane >> 4, t16 = lane & 15;
    f32x4 acc[4][4] = {};
    gemm_core(A1, A2, Wt, As, Bs, row0, col0, wave, lane, acc);
    // swapped layout: row = row0+wm*64+mi*16+t16; cols = col0+wn*64+ni*16+q*4+{0..3}
    f32x4 bv[4];
#pragma unroll
    for (int ni = 0; ni < 4; ++ni)
        bv[ni] = *(const f32x4*)(bias + col0 + wn * 64 + ni * 16 + q * 4);
#pragma unroll
    for (int mi = 0; mi < 4; ++mi) {
        int row = row0 + wm * 64 + mi * 16 + t16;
        if (row < N_NODES_C) {
#pragma unroll
            for (int ni = 0; ni < 4; ++ni) {
                int colq = col0 + wn * 64 + ni * 16 + q * 4;
                float v0 = eluf(acc[mi][ni][0] + bv[ni][0]);
                float v1 = eluf(acc[mi][ni][1] + bv[ni][1]);
                float v2 = eluf(acc[mi][ni][2] + bv[ni][2]);
                float v3 = eluf(acc[mi][ni][3] + bv[ni][3]);
                bf16x4 ob;
                ob[0] = f2bf(v0); ob[1] = f2bf(v1);
                ob[2] = f2bf(v2); ob[3] = f2bf(v3);
                *(bf16x4*)(C + (size_t)row * DIM + colq) = ob;
                *(unsigned*)(C8 + (size_t)row * DIM + colq) =
                    f32x4_to_fp8(v0, v1, v2, v3);
            }
        }
    }
}

__global__ __launch_bounds__(256, 4)
void k_gemm_pool_mfma(const short* __restrict__ A1, const short* __restrict__ A2,
                      const short* __restrict__ Wt, const float* __restrict__ bias,
                      const int* __restrict__ batch, float* __restrict__ gsum) {
    __shared__ __align__(16) short As[128 * 64];
    __shared__ __align__(16) short Bs[128 * 64];
    const int L = blockIdx.x;
    const int ct = (L & 31) >> 3;
    const int rt = ((L >> 5) << 3) + (L & 7);
    if (rt >= NROWT) return;
    const int row0 = rt * 128, col0 = ct * 128;
    const int tid = threadIdx.x;
    const int lane = tid & 63, wave = tid >> 6;
    const int wm = wave >> 1, wn = wave & 1;
    const int q = lane >> 4, t16 = lane & 15;
    f32x4 acc[4][4] = {};
    gemm_core(A1, A2, Wt, As, Bs, row0, col0, wave, lane, acc);
    // batch loads direct from global (L2-broadcast). Rows OOB -> -1 sentinel.
    auto ldb = [&](int r) { return (r < N_NODES_C) ? batch[r] : -1; };
    f32x4 bv[4];
#pragma unroll
    for (int ni = 0; ni < 4; ++ni)
        bv[ni] = *(const f32x4*)(bias + col0 + wn * 64 + ni * 16 + q * 4);
    const int g0 = ldb(row0 + wm * 64);
    const int g63 = ldb(row0 + wm * 64 + 63);
    if (g0 == g63) {
        if (g0 >= 0) {
            // single graph for whole wave: per-thread col sums over 4 rows,
            // butterfly-reduce across the 16-lane t16 group, 16 atomics/wave
#pragma unroll
            for (int ni = 0; ni < 4; ++ni) {
#pragma unroll
                for (int r = 0; r < 4; ++r) {
                    float s = 0.0f;
#pragma unroll
                    for (int mi = 0; mi < 4; ++mi)
                        s += eluf(acc[mi][ni][r] + bv[ni][r]);
                    s += __shfl_xor(s, 1, 64);
                    s += __shfl_xor(s, 2, 64);
                    s += __shfl_xor(s, 4, 64);
                    s += __shfl_xor(s, 8, 64);
                    if (t16 == 0)
                        atomicAdd(&gsum[(size_t)g0 * DIM + col0 + wn * 64 +
                                        ni * 16 + q * 4 + r], s);
                }
            }
        }
    } else if (g0 >= 0) {
        // graph boundary inside wave (rare). batch is SORTED -> graphs in
        // this wave form the contiguous range [g0, gmx]. Loop over it with
        // graph-masked butterfly reduces: same conflict-free atomic pattern
        // as the fast path.
        int g_th[4];
#pragma unroll
        for (int mi = 0; mi < 4; ++mi) g_th[mi] = ldb(row0 + wm * 64 + mi * 16 + t16);
        int gmx = g0;
#pragma unroll
        for (int mi = 0; mi < 4; ++mi) gmx = max(gmx, g_th[mi]);
        gmx = max(gmx, __shfl_xor(gmx, 1, 64));
        gmx = max(gmx, __shfl_xor(gmx, 2, 64));
        gmx = max(gmx, __shfl_xor(gmx, 4, 64));
        gmx = max(gmx, __shfl_xor(gmx, 8, 64));   // wave-uniform max
        for (int gsel = g0; gsel <= gmx; ++gsel) {
#pragma unroll
            for (int ni = 0; ni < 4; ++ni) {
#pragma unroll
                for (int r = 0; r < 4; ++r) {
                    float s = 0.0f;
#pragma unroll
                    for (int mi = 0; mi < 4; ++mi) {
                        float v = eluf(acc[mi][ni][r] + bv[ni][r]);
                        s += (g_th[mi] == gsel) ? v : 0.0f;
                    }
                    s += __shfl_xor(s, 1, 64);
                    s += __shfl_xor(s, 2, 64);
                    s += __shfl_xor(s, 4, 64);
                    s += __shfl_xor(s, 8, 64);
                    if (t16 == 0)
                        atomicAdd(&gsum[(size_t)gsel * DIM + col0 + wn * 64 +
                                        ni * 16 + q * 4 + r], s);
                }
            }
        }
    }
}

// out[g,j] = (gsum[g,:]/max(cnt[g],1)) @ Wc[:,j] + bc[j]
// one wave per (graph, class): lanes stride c, shfl-reduce (was 640 threads
// total each looping 512 serially).
__global__ __launch_bounds__(NUM_CLASSES_C * 64)
void k_final(const float* __restrict__ gsum, const int* __restrict__ cnt,
             const float* __restrict__ Wc, const float* __restrict__ bc,
             float* __restrict__ out) {
    int g = blockIdx.x;
    int j = threadIdx.x >> 6;          // class = wave id
    int l = threadIdx.x & 63;
    int c_ = cnt[g];
    float inv = 1.0f / (float)(c_ > 1 ? c_ : 1);
    float s = 0.0f;
    for (int c = l; c < DIM; c += 64)
        s += gsum[(size_t)g * DIM + c] * Wc[(size_t)c * NUM_CLASSES_C + j];
    s += __shfl_xor(s, 1, 64);
    s += __shfl_xor(s, 2, 64);
    s += __shfl_xor(s, 4, 64);
    s += __shfl_xor(s, 8, 64);
    s += __shfl_xor(s, 16, 64);
    s += __shfl_xor(s, 32, 64);
    if (l == 0) out[g * NUM_CLASSES_C + j] = s * inv + bc[j];
}

// ---------------- launch ----------------

extern "C" void kernel_launch(void* const* d_in, const int* in_sizes, int n_in,
                              void* d_out, int out_size, void* d_ws, size_t ws_size,
                              hipStream_t stream) {
    const float* x   = (const float*)d_in[0];
    const int*   ei  = (const int*)d_in[1];
    const int*   src = ei;
    const int*   dst = ei + N_EDGES_C;
    const int* batch = (const int*)d_in[2];
    const float* Hm1 = (const float*)d_in[3];
    const float* Wp1 = (const float*)d_in[4];
    const float* Ws1 = (const float*)d_in[5];
    const float* b1  = (const float*)d_in[6];
    const float* Hm2 = (const float*)d_in[7];
    const float* Wp2 = (const float*)d_in[8];
    const float* Ws2 = (const float*)d_in[9];
    const float* b2  = (const float*)d_in[10];
    const float* Wc  = (const float*)d_in[11];
    const float* bc  = (const float*)d_in[12];
    float* out = (float*)d_out;

    char* ws = (char*)d_ws;
    size_t off = 0;
    auto alloc = [&](size_t bytes) {
        void* p = ws + off;
        off += (bytes + 255) & ~(size_t)255;
        return p;
    };
    const size_t nodeB16 = (size_t)N_NODES_C * DIM * 2;  // 51.2 MB
    const size_t nodeB8  = (size_t)N_NODES_C * DIM;      // 25.6 MB
    short* xb    = (short*)alloc(nodeB16);
    short* aggB  = (short*)alloc(nodeB16);
    short* hB    = (short*)alloc(nodeB16);
    unsigned char* xq = (unsigned char*)alloc(nodeB8);   // fp8 shadow of x
    unsigned char* hq = (unsigned char*)alloc(nodeB8);   // fp8 shadow of h1
    float* Weff1 = (float*)alloc((size_t)DIM * DIM * 4);
    float* Weff2 = (float*)alloc((size_t)DIM * DIM * 4);
    short* Wt1   = (short*)alloc((size_t)DIM * 2 * DIM * 2);
    short* Wt2   = (short*)alloc((size_t)DIM * 2 * DIM * 2);
    int*   cnt_i = (int*)alloc((size_t)N_NODES_C * 4);
    int*   start = (int*)alloc((size_t)(N_NODES_C + 1) * 4);
    int*   cursor= (int*)alloc((size_t)N_NODES_C * 4);
    int*   ebuf  = (int*)alloc((size_t)N_EDGES_C * 4);
    int*   cnt   = (int*)alloc((size_t)NUM_GRAPHS_C * 4);
    float* gsum  = (float*)alloc((size_t)NUM_GRAPHS_C * DIM * 4);
    int*   bsum  = (int*)alloc((size_t)SCAN_NBLK * 4);

    hipMemsetAsync(cnt_i, 0, (size_t)N_NODES_C * 4, stream);
    hipMemsetAsync(cnt, 0, (size_t)NUM_GRAPHS_C * 4, stream);
    hipMemsetAsync(gsum, 0, (size_t)NUM_GRAPHS_C * DIM * 4, stream);

    // CSR build + weight prep + casts
    k_hist<<<(N_EDGES_C + 255) / 256, 256, 0, stream>>>(src, cnt_i);
    k_bsum<<<SCAN_NBLK, 1024, 0, stream>>>(cnt_i, bsum, batch, cnt);
    k_scan_apply<<<SCAN_NBLK, 1024, 0, stream>>>(cnt_i, bsum, start, cursor);
    k_fill<<<(N_EDGES_C + 255) / 256, 256, 0, stream>>>(src, dst, cursor, ebuf);
    k_weff<<<DIM, 128, 0, stream>>>(Hm1, Wp1, Weff1);
    k_weff<<<DIM, 128, 0, stream>>>(Hm2, Wp2, Weff2);
    k_prepw<<<128, 256, 0, stream>>>(Weff1, Ws1, Wt1);
    k_prepw<<<128, 256, 0, stream>>>(Weff2, Ws2, Wt2);
    k_cast<<<(N_NODES_C * DIM / 8 + 255) / 256, 256, 0, stream>>>(x, xb, xq);

    // layer 1
    k_gather_8<<<(N_NODES_C + 3) / 4, 256, 0, stream>>>(xq, start, ebuf, xb, aggB);
    k_gemm_elu_mfma<<<GEMM_BLOCKS, 256, 0, stream>>>(aggB, xb, Wt1, b1, hB, hq);

    // layer 2
    k_gather_8<<<(N_NODES_C + 3) / 4, 256, 0, stream>>>(hq, start, ebuf, hB, aggB);
    k_gemm_pool_mfma<<<GEMM_BLOCKS, 256, 0, stream>>>(aggB, hB, Wt2, b2, batch, gsum);

    k_final<<<NUM_GRAPHS_C, NUM_CLASSES_C * 64, 0, stream>>>(gsum, cnt, Wc, bc, out);
}